// Round 13
// baseline (67715.039 us; speedup 1.0000x reference)
//
#include <hip/hip_runtime.h>
#include <hip/hip_bf16.h>

// Dims (fixed by the reference)
#define SLEN 4096
#define CLEN 12
#define ECD  256
#define HCD  256
#define ED   1024
#define HD   1024
#define TD   64
#define NSLOT 32          // WGs per XCD group (32 units each)
#define POLL_LIMIT 2048   // dead-group bailout << live runtime
#define GATE_LIMIT 200000 // precomp tile-gate bailout (hang protection)

typedef unsigned  uv4 __attribute__((ext_vector_type(4)));
typedef __attribute__((ext_vector_type(8))) short bf16x8;   // MFMA A/B frag
typedef __attribute__((ext_vector_type(4))) float f32x4;    // MFMA C/D frag

#if defined(__has_builtin)
#if __has_builtin(__builtin_amdgcn_sdot4)
#define HAVE_SDOT4 1
#endif
#if __has_builtin(__builtin_amdgcn_perm)
#define HAVE_PERM 1
#endif
#endif

#ifdef HAVE_PERM
#define PERM2(hi, lo) __builtin_amdgcn_perm((unsigned)(hi), (unsigned)(lo), 0x05040100u)
#else
#define PERM2(hi, lo) ((((unsigned)(lo)) & 0xFFFFu) | (((unsigned)(hi)) << 16))
#endif

// global -> LDS direct (16B/lane). LDS dest = wave-uniform base + lane*16.
#define GLOAD_LDS16(g, l)                                                    \
    __builtin_amdgcn_global_load_lds(                                        \
        (const __attribute__((address_space(1))) void*)(g),                  \
        (__attribute__((address_space(3))) void*)(l), 16, 0, 0)

__device__ __forceinline__ float sigmoidf_(float x) { return 1.f / (1.f + __expf(-x)); }
__device__ __forceinline__ float tanh_fast(float x) {
    float ax = fabsf(x);
    float e = __expf(2.f * ax);          // inf-safe
    float t = 1.f - 2.f / (e + 1.f);
    return copysignf(t, x);
}
__device__ __forceinline__ unsigned short bf16r(float f) {
    unsigned u = __float_as_uint(f);
    return (unsigned short)((u + 0x7FFFu + ((u >> 16) & 1u)) >> 16);
}

// ===========================================================================
// prep_all: all one-time conversions + control-buffer init in ONE launch.
// ===========================================================================
__global__ __launch_bounds__(256) void prep_all(
    const float* __restrict__ Wih,  unsigned short* __restrict__ Wihb,
    const float* __restrict__ Wec,  const float* __restrict__ Wihc,
    const float* __restrict__ bihc, const float* __restrict__ bhhc,
    float* __restrict__ table,
    const float* __restrict__ Whhc, unsigned short* __restrict__ Wt,
    const float* __restrict__ Wtag, unsigned short* __restrict__ Wtagb,
    unsigned* __restrict__ hdata, int* __restrict__ xcd_ctr,
    const int* __restrict__ word_idx, const float* __restrict__ Wemb,
    unsigned short* __restrict__ Xw, int* __restrict__ done)
{
    const int b = blockIdx.x, tid = threadIdx.x;
    if (b < 2560) {
        int i = b * 256 + tid;
        const float4* s = reinterpret_cast<const float4*>(Wih + (size_t)i * 8);
        float4 a = s[0], b2 = s[1];
        unsigned short o[8] = { bf16r(a.x), bf16r(a.y), bf16r(a.z), bf16r(a.w),
                                bf16r(b2.x), bf16r(b2.y), bf16r(b2.z), bf16r(b2.w) };
        *reinterpret_cast<uint4*>(Wihb + (size_t)i * 8) = *reinterpret_cast<uint4*>(o);
    } else if (b < 2664) {
        int id = (b - 2560) * 256 + tid;
        if (id < 26 * 1024) {
            int c = id >> 10, rp = id & 1023;
            int u = rp >> 2, g = rp & 3, row = g * 256 + u;
            const float4* a = reinterpret_cast<const float4*>(Wec + (size_t)c * 256);
            const float4* bb = reinterpret_cast<const float4*>(Wihc + (size_t)row * 256);
            float acc = 0.f;
            #pragma unroll 16
            for (int k = 0; k < 64; ++k) {
                float4 av = a[k], bv = bb[k];
                acc += av.x * bv.x + av.y * bv.y + av.z * bv.z + av.w * bv.w;
            }
            table[id] = acc + bihc[row] + bhhc[row];
        }
    } else if (b < 2792) {
        int id = (b - 2664) * 256 + tid;
        int C = id >> 5, kg = id & 31;
        int h = C >> 9, rem = C & 511, g = rem >> 7, ul = rem & 127;
        int row = g * 256 + h * 128 + ul;
        const float4* sv = reinterpret_cast<const float4*>(
            Whhc + (size_t)row * 256 + kg * 8);
        float4 a = sv[0], b2 = sv[1];
        unsigned short o[8] = { bf16r(a.x), bf16r(a.y), bf16r(a.z), bf16r(a.w),
                                bf16r(b2.x), bf16r(b2.y), bf16r(b2.z), bf16r(b2.w) };
        *reinterpret_cast<uint4*>(Wt + (size_t)(kg * 1024 + C) * 8) =
            *reinterpret_cast<uint4*>(o);
    } else if (b < 2824) {
        int i = (b - 2792) * 256 + tid;
        const float4* s = reinterpret_cast<const float4*>(Wtag + (size_t)i * 8);
        float4 a = s[0], b2 = s[1];
        unsigned short o[8] = { bf16r(a.x), bf16r(a.y), bf16r(a.z), bf16r(a.w),
                                bf16r(b2.x), bf16r(b2.y), bf16r(b2.z), bf16r(b2.w) };
        *reinterpret_cast<uint4*>(Wtagb + (size_t)i * 8) = *reinterpret_cast<uint4*>(o);
    } else if (b < 2856) {
        hdata[(b - 2824) * 256 + tid] = 0xFFFF0000u;   // tag 0xFFFF
    } else if (b < 4904) {
        int id = (b - 2856) * 256 + tid;              // 4096 rows x 128 chunks
        int row = id >> 7, c8 = id & 127;
        int k = c8 * 8;
        const float4* sv = reinterpret_cast<const float4*>(
            Wemb + (size_t)word_idx[row] * 1024 + k);
        float4 a = sv[0], b2 = sv[1];
        unsigned short o[8] = { bf16r(a.x), bf16r(a.y), bf16r(a.z), bf16r(a.w),
                                bf16r(b2.x), bf16r(b2.y), bf16r(b2.z), bf16r(b2.w) };
        *reinterpret_cast<uint4*>(Xw + (size_t)row * 1280 + k) =
            *reinterpret_cast<uint4*>(o);
    } else {
        if (tid < 8) xcd_ctr[tid] = 0;
        if (tid >= 32 && tid < 64) done[tid - 32] = 0;
    }
}

// ===========================================================================
// Fused char LSTM (unchanged): ALL 12 steps, 128 WGs x 32 words; epilogue
// writes Xw cols 1024..1280 directly.
// ===========================================================================
__global__ __launch_bounds__(256) void char_fused(
    const int* __restrict__ char_idx,
    const unsigned short* __restrict__ Wt,   // [32 kg][1024 C][8] bf16
    const float* __restrict__ table,         // [26][1024]
    unsigned short* __restrict__ Xw)         // out [4096][1280], cols 1024..1280
{
    __shared__ unsigned short hA[2][8192];   // 2 x [32 words][256] bf16, swizzled
    __shared__ int cidx_s[32 * CLEN];

    const int tid  = threadIdx.x;
    const int lane = tid & 63;
    const int wv   = tid >> 6;       // wave 0..3
    const int fr   = lane & 15;
    const int fkq  = lane >> 4;      // 0..3
    const int w0   = blockIdx.x * 32;

    for (int e = tid; e < 32 * CLEN; e += 256)
        cidx_s[e] = char_idx[(w0 + (e / CLEN)) * CLEN + (e % CLEN)];
    {   // zero hA[0] (h_{-1} = 0)
        uint4 z; z.x = z.y = z.z = z.w = 0u;
        for (int e = tid; e < 1024; e += 256)
            *reinterpret_cast<uint4*>(&hA[0][e * 8]) = z;
    }
    __syncthreads();

    float cst[32];
    #pragma unroll
    for (int i = 0; i < 32; ++i) cst[i] = 0.f;

    for (int t = 0; t < CLEN; ++t) {
        const int cur = t & 1, nxt = cur ^ 1;
        #pragma unroll
        for (int h = 0; h < 2; ++h) {
            f32x4 acc[2][8];
            #pragma unroll
            for (int m = 0; m < 2; ++m)
                #pragma unroll
                for (int i = 0; i < 8; ++i) acc[m][i] = f32x4{0.f, 0.f, 0.f, 0.f};

            #pragma unroll
            for (int k0i = 0; k0i < 8; ++k0i) {
                const int kg = k0i * 4 + fkq;
                bf16x8 af[2];
                #pragma unroll
                for (int m = 0; m < 2; ++m) {
                    const int row = m * 16 + fr;
                    af[m] = *reinterpret_cast<const bf16x8*>(
                        &hA[cur][row * 256 + ((kg ^ ((row & 7) << 2)) << 3)]);
                }
                #pragma unroll
                for (int i = 0; i < 8; ++i) {
                    const int T = wv + (i << 2);               // tile 0..31
                    const int col = h * 512 + T * 16 + fr;     // gate-blocked col
                    const bf16x8 bf = *reinterpret_cast<const bf16x8*>(
                        Wt + (size_t)(kg * 1024 + col) * 8);
                    acc[0][i] = __builtin_amdgcn_mfma_f32_16x16x32_bf16(
                        af[0], bf, acc[0][i], 0, 0, 0);
                    acc[1][i] = __builtin_amdgcn_mfma_f32_16x16x32_bf16(
                        af[1], bf, acc[1][i], 0, 0, 0);
                }
            }

            // cell update: lane owns gates of 2 units x 8 words (i = 2g + ab)
            #pragma unroll
            for (int m = 0; m < 2; ++m) {
                #pragma unroll
                for (int r = 0; r < 4; ++r) {
                    const int wl = m * 16 + (lane >> 4) * 4 + r;  // word local
                    const int ci = cidx_s[wl * CLEN + t];
                    #pragma unroll
                    for (int ab = 0; ab < 2; ++ab) {
                        const int u = h * 128 + (wv + 4 * ab) * 16 + fr; // unit
                        const float4 tv = *reinterpret_cast<const float4*>(
                            table + (size_t)ci * 1024 + u * 4);
                        const int cix = ((h * 2 + m) * 2 + ab) * 4 + r;
                        const float gi_ = acc[m][0 + ab][r] + tv.x;
                        const float gf_ = acc[m][2 + ab][r] + tv.y;
                        const float gg_ = acc[m][4 + ab][r] + tv.z;
                        const float go_ = acc[m][6 + ab][r] + tv.w;
                        const float i_ = sigmoidf_(gi_), f_ = sigmoidf_(gf_);
                        const float g_ = tanh_fast(gg_), o_ = sigmoidf_(go_);
                        const float cn = f_ * cst[cix] + i_ * g_;
                        cst[cix] = cn;
                        const unsigned short hb = bf16r(o_ * tanh_fast(cn));
                        const int chn = u >> 3;
                        hA[nxt][wl * 256 + ((chn ^ ((wl & 7) << 2)) << 3) + (u & 7)] = hb;
                    }
                }
            }
        }
        __syncthreads();   // hA[nxt] complete before next step's GEMM
    }

    // final h (12 steps -> buffer 0) -> Xw cols 1024..1280, de-swizzled
    for (int e = tid; e < 1024; e += 256) {
        const int w = e >> 5, ch = e & 31;
        uint4 v = *reinterpret_cast<uint4*>(
            &hA[0][w * 256 + ((ch ^ ((w & 7) << 2)) << 3)]);
        *reinterpret_cast<uint4*>(
            Xw + (size_t)(w0 + w) * 1280 + 1024 + ch * 8) = v;
    }
}

// ===========================================================================
// word_mega: block-role fusion.
//   blocks [0,256)    : word LSTM recurrence (R12 word_rec verbatim +
//                       setprio(1) + tile gate every 128 steps).
//   blocks [256,1280) : tiled precomp GEMM (R12 gemm_bf16_bt verbatim, but
//                       sc0 sc1 C-stores + done[mt] atomic publish).
// Word blocks dispatched FIRST -> all resident; gemm blocks co-schedule on
// leftover CU capacity (LDS 32KB -> 4 blocks/CU), producing row-blocks in
// ascending-t order far ahead of consumption. Producers never wait; the
// consumer gate has a bailout (deadlock-free).
// ===========================================================================
__global__ __launch_bounds__(256) void word_mega(
    float* __restrict__ precomp, const float* __restrict__ W_hh,
    unsigned* __restrict__ hs_b, unsigned* hdata, int* xcd_ctr,
    const unsigned short* __restrict__ Xw,
    const unsigned short* __restrict__ Wihb,
    const float* __restrict__ bih, const float* __restrict__ bhh,
    int* __restrict__ done)
{
    __shared__ unsigned short As[128 * 64];
    __shared__ unsigned short Bs[128 * 64];
    __shared__ int s_vals[2];

    const int tid  = threadIdx.x;
    const int lane = tid & 63;
    const int wv   = tid >> 6;

    if (blockIdx.x >= 256) {
        // ------------------- producer: tiled GEMM -------------------
        const int g  = blockIdx.x - 256;
        const int n0 = (g & 31) * 128;
        const int mt = g >> 5;
        const int m0 = mt * 128;
        const int K = 1280, N = 4096;
        const int wm = wv >> 1, wn = wv & 1;
        const int fr = lane & 15, fk = lane >> 4;

        int srcA[4], srcB[4], ldsb[4];
        #pragma unroll
        for (int c = 0; c < 4; ++c) {
            int ch = c * 256 + wv * 64 + lane;
            int row = ch >> 3, chunk = ch & 7;
            int swc = chunk ^ (row & 7);
            srcA[c] = (m0 + row) * K + swc * 8;
            srcB[c] = (n0 + row) * K + swc * 8;
            ldsb[c] = (c * 256 + wv * 64) * 8;
        }

        f32x4 acc[4][4];
        #pragma unroll
        for (int i = 0; i < 4; ++i)
            #pragma unroll
            for (int j = 0; j < 4; ++j) acc[i][j] = f32x4{0.f, 0.f, 0.f, 0.f};

        for (int k0 = 0; k0 < K; k0 += 64) {
            if (k0 > 0) __syncthreads();
            #pragma unroll
            for (int c = 0; c < 4; ++c) {
                GLOAD_LDS16(Xw + srcA[c] + k0, As + ldsb[c]);
                GLOAD_LDS16(Wihb + srcB[c] + k0, Bs + ldsb[c]);
            }
            asm volatile("s_waitcnt vmcnt(0)" ::: "memory");
            __syncthreads();
            #pragma unroll
            for (int ks = 0; ks < 2; ++ks) {
                bf16x8 af[4], bfr[4];
                #pragma unroll
                for (int i = 0; i < 4; ++i) {
                    int ra = wm * 64 + i * 16 + fr;
                    af[i] = *reinterpret_cast<const bf16x8*>(
                        &As[ra * 64 + (((ks * 4 + fk) ^ (ra & 7)) << 3)]);
                    int rb = wn * 64 + i * 16 + fr;
                    bfr[i] = *reinterpret_cast<const bf16x8*>(
                        &Bs[rb * 64 + (((ks * 4 + fk) ^ (rb & 7)) << 3)]);
                }
                #pragma unroll
                for (int i = 0; i < 4; ++i)
                    #pragma unroll
                    for (int j = 0; j < 4; ++j)
                        acc[i][j] = __builtin_amdgcn_mfma_f32_16x16x32_bf16(
                            af[i], bfr[j], acc[i][j], 0, 0, 0);
            }
        }

        const int colb = n0 + wn * 64 + fr;
        float bsum[4];
        #pragma unroll
        for (int j = 0; j < 4; ++j)
            bsum[j] = bih[colb + j * 16] + bhh[colb + j * 16];
        const int fk4 = fk;
        #pragma unroll
        for (int i = 0; i < 4; ++i) {
            int row0 = m0 + wm * 64 + i * 16 + fk4 * 4;
            #pragma unroll
            for (int j = 0; j < 4; ++j) {
                int col = colb + j * 16;
                #pragma unroll
                for (int r = 0; r < 4; ++r) {
                    float vst = acc[i][j][r] + bsum[j];
                    float* ad = precomp + (size_t)(row0 + r) * N + col;
                    asm volatile("global_store_dword %0, %1, off sc0 sc1"
                                 :: "v"(ad), "v"(vst) : "memory");
                }
            }
        }
        asm volatile("s_waitcnt vmcnt(0)" ::: "memory");
        __syncthreads();              // all waves' stores drained
        if (tid == 0) atomicAdd(&done[mt], 1);
        return;
    }

    // ------------------- consumer: word recurrence -------------------
    __builtin_amdgcn_s_setprio(1);    // keep VALU issue priority over gemm waves

    const int v = wv;
    const int q = lane >> 5;
    const int m = lane & 31;
    const int j = lane & 7;

    if (tid == 0) {
        unsigned xcc;
        asm volatile("s_getreg_b32 %0, hwreg(HW_REG_XCC_ID)" : "=s"(xcc));
        xcc &= 7u;
        s_vals[0] = (int)xcc;
        s_vals[1] = atomicAdd(&xcd_ctr[xcc], 1);
    }
    __syncthreads();
    const int xcc  = s_vals[0];
    const int slot = s_vals[1];
    if (slot >= NSLOT) return;

    const int base_u = slot * 32 + v * 8;
    unsigned* hdata_x = hdata + xcc * 1024;   // 2 parities x 512 tagged dwords

    // --- W_hh slice -> int8 registers: 16 rows x 32 cols, per-row scale ---
    int   wq[16][8];
    float scl[16];
    #pragma unroll
    for (int r = 0; r < 16; ++r) {
        const int grow = (2 * q + (r >> 3)) * 1024 + base_u + (r & 7);
        const float4* rp = reinterpret_cast<const float4*>(
            W_hh + (size_t)grow * 1024 + 32 * m);
        float wv_[32];
        float mx = 0.f;
        #pragma unroll
        for (int d = 0; d < 8; ++d) {
            float4 f = rp[d];
            wv_[4*d+0] = f.x; wv_[4*d+1] = f.y; wv_[4*d+2] = f.z; wv_[4*d+3] = f.w;
            mx = fmaxf(mx, fmaxf(fmaxf(fabsf(f.x), fabsf(f.y)),
                                 fmaxf(fabsf(f.z), fabsf(f.w))));
        }
        mx = fmaxf(mx, __shfl_xor(mx, 1));
        mx = fmaxf(mx, __shfl_xor(mx, 2));
        mx = fmaxf(mx, __shfl_xor(mx, 4));
        mx = fmaxf(mx, __shfl_xor(mx, 8));
        mx = fmaxf(mx, __shfl_xor(mx, 16));
        const float inv = (mx > 0.f) ? (127.f / mx) : 0.f;
        scl[r] = mx * (1.f / (127.f * 127.f));
        #pragma unroll
        for (int d = 0; d < 8; ++d) {
            int b0 = (int)rintf(wv_[4*d+0] * inv) & 255;
            int b1 = (int)rintf(wv_[4*d+1] * inv) & 255;
            int b2 = (int)rintf(wv_[4*d+2] * inv) & 255;
            int b3 = (int)rintf(wv_[4*d+3] * inv) & 255;
            wq[r][d] = b0 | (b1 << 8) | (b2 << 16) | (b3 << 24);
        }
    }

#ifdef HAVE_SDOT4
    #define DOT4(a, b, c) __builtin_amdgcn_sdot4((a), (b), (c), false)
#else
    #define DOT4(a, b, c) ({ int _d; \
        asm("v_dot4_i32_i8 %0, %1, %2, %3" : "=v"(_d) : "v"(a), "v"(b), "v"(c)); _d; })
#endif

    float c_reg = 0.f;

    for (int t = 0; t < SLEN; ++t) {
        const int pp = (t + 1) & 1;
        const int pc = t & 1;

        // tile gate: wait until row-block t/128 fully produced (32 col-tiles)
        if ((t & 127) == 0) {
            const int* dp2 = done + (t >> 7);
            int dv, itg = 0;
            for (;;) {
                asm volatile("global_load_dword %0, %1, off sc0 sc1\n\t"
                             "s_waitcnt vmcnt(0)"
                             : "=v"(dv) : "v"(dp2) : "memory");
                if (dv >= 32) break;
                if (++itg > GATE_LIMIT) return;
                __builtin_amdgcn_s_sleep(8);
            }
        }

        // prefetch precomp gate biases (overlaps the poll wait)
        float pre0 = 0.f, pre1 = 0.f, pre2 = 0.f, pre3 = 0.f;
        if (lane < 8) {
            const float* pr = precomp + (size_t)t * 4096 + base_u + j;
            pre0 = pr[0]; pre1 = pr[1024]; pre2 = pr[2048]; pre3 = pr[3072];
        }

        // --- single-trip acquire: poll 16 tagged dwords ---
        int hq[8];
        if (t > 0) {
            const unsigned tw = ((unsigned)(t - 1)) << 16;
            const unsigned* dp = hdata_x + pp * 512 + 16 * m;
            uv4 w0_, w1_, w2_, w3_;
            int it = 0; bool dead = false;
            for (;;) {
                asm volatile(
                    "global_load_dwordx4 %0, %4, off sc0\n\t"
                    "global_load_dwordx4 %1, %4, off offset:16 sc0\n\t"
                    "global_load_dwordx4 %2, %4, off offset:32 sc0\n\t"
                    "global_load_dwordx4 %3, %4, off offset:48 sc0\n\t"
                    "s_waitcnt vmcnt(0)"
                    : "=&v"(w0_), "=&v"(w1_), "=&v"(w2_), "=&v"(w3_)
                    : "v"(dp) : "memory");
                unsigned bad =
                    (w0_.x ^ tw) | (w0_.y ^ tw) | (w0_.z ^ tw) | (w0_.w ^ tw) |
                    (w1_.x ^ tw) | (w1_.y ^ tw) | (w1_.z ^ tw) | (w1_.w ^ tw) |
                    (w2_.x ^ tw) | (w2_.y ^ tw) | (w2_.z ^ tw) | (w2_.w ^ tw) |
                    (w3_.x ^ tw) | (w3_.y ^ tw) | (w3_.z ^ tw) | (w3_.w ^ tw);
                if (__all((bad & 0xFFFF0000u) == 0u)) break;
                if (++it > POLL_LIMIT) { dead = true; break; }
            }
            if (dead) return;
            hq[0] = (int)PERM2(w0_.y, w0_.x);
            hq[1] = (int)PERM2(w0_.w, w0_.z);
            hq[2] = (int)PERM2(w1_.y, w1_.x);
            hq[3] = (int)PERM2(w1_.w, w1_.z);
            hq[4] = (int)PERM2(w2_.y, w2_.x);
            hq[5] = (int)PERM2(w2_.w, w2_.z);
            hq[6] = (int)PERM2(w3_.y, w3_.x);
            hq[7] = (int)PERM2(w3_.w, w3_.z);
        } else {
            #pragma unroll
            for (int i = 0; i < 8; ++i) hq[i] = 0;
        }

        // --- 16 rows: int8 dot4 (2 indep chains) + exact int32 butterfly ---
        float self = 0.f;
        #pragma unroll
        for (int r = 0; r < 16; ++r) {
            int a0 = 0, a1 = 0;
            #pragma unroll
            for (int d = 0; d < 4; ++d) {
                a0 = DOT4(wq[r][d],     hq[d],     a0);
                a1 = DOT4(wq[r][4 + d], hq[4 + d], a1);
            }
            int s = a0 + a1;
            s += __shfl_xor(s, 1);  s += __shfl_xor(s, 2);
            s += __shfl_xor(s, 4);  s += __shfl_xor(s, 8);
            s += __shfl_xor(s, 16);
            self = ((lane & 31) == r) ? (float)s * scl[r] : self;
        }

        const float gi = __shfl(self, j);
        const float gf = __shfl(self, 8 + j);
        const float gg = __shfl(self, 32 + j);
        const float go = __shfl(self, 40 + j);

        float h = 0.f;
        if (lane < 8) {
            const float i_ = sigmoidf_(gi + pre0);
            const float f_ = sigmoidf_(gf + pre1);
            const float g_ = tanh_fast(gg + pre2);
            const float o_ = sigmoidf_(go + pre3);
            c_reg = f_ * c_reg + i_ * g_;
            h = o_ * tanh_fast(c_reg);
        }

        // publish: bf16 pairs for tag stage + self-validating tagged int8 pairs
        const float hn = __shfl_down(h, 1);
        int qv = (int)rintf(fminf(fmaxf(h * 127.f, -127.f), 127.f));
        const int qn = __shfl(qv, lane | 1);
        if (lane < 8 && (lane & 1) == 0) {
            unsigned pb = (unsigned)bf16r(h) | ((unsigned)bf16r(hn) << 16);
            hs_b[(size_t)t * 512 + (base_u >> 1) + (lane >> 1)] = pb;
            unsigned pk = ((unsigned)t << 16) | ((unsigned)(qn & 255) << 8)
                        | (unsigned)(qv & 255);
            unsigned* dpw = hdata_x + pc * 512 + slot * 16 + v * 4 + (lane >> 1);
            asm volatile("global_store_dword %0, %1, off sc0"
                         :: "v"(dpw), "v"(pk) : "memory");
        }
    }
    #undef DOT4
}

// ===========================================================================
// Tag projection (MFMA) + fused log_softmax (unchanged).
// ===========================================================================
__global__ __launch_bounds__(256) void tag_mfma(
    const unsigned short* __restrict__ A,     // hs_b as bf16 [4096][1024]
    const unsigned short* __restrict__ B,     // Wtagb [64][1024]
    const float* __restrict__ btag, float* __restrict__ out)
{
    __shared__ unsigned short As[128 * 64];
    __shared__ unsigned short Bs[64 * 64];
    __shared__ float ts[128 * 65];

    const int tid  = threadIdx.x;
    const int lane = tid & 63;
    const int wm = (tid >> 6) >> 1, wn = (tid >> 6) & 1;
    const int fr = lane & 15, fk = lane >> 4;
    const int m0 = blockIdx.x * 128;

    uint4 ar[4], br[2];
    int rowa[4], kca[4], rowb[2], kcb[2];
    #pragma unroll
    for (int c = 0; c < 4; ++c) {
        int ch = c * 256 + tid;
        rowa[c] = ch >> 3; kca[c] = ch & 7;
    }
    #pragma unroll
    for (int c = 0; c < 2; ++c) {
        int ch = c * 256 + tid;
        rowb[c] = ch >> 3; kcb[c] = ch & 7;
    }

    auto load_tiles = [&](int k0) {
        #pragma unroll
        for (int c = 0; c < 4; ++c)
            ar[c] = *reinterpret_cast<const uint4*>(
                A + (size_t)(m0 + rowa[c]) * 1024 + k0 + kca[c] * 8);
        #pragma unroll
        for (int c = 0; c < 2; ++c)
            br[c] = *reinterpret_cast<const uint4*>(
                B + (size_t)rowb[c] * 1024 + k0 + kcb[c] * 8);
    };

    f32x4 acc[4][2];
    #pragma unroll
    for (int i = 0; i < 4; ++i)
        #pragma unroll
        for (int j = 0; j < 2; ++j) acc[i][j] = f32x4{0.f, 0.f, 0.f, 0.f};

    load_tiles(0);
    for (int k0 = 0; k0 < 1024; k0 += 64) {
        __syncthreads();
        #pragma unroll
        for (int c = 0; c < 4; ++c) {
            int sw = kca[c] ^ (rowa[c] & 7);
            *reinterpret_cast<uint4*>(&As[rowa[c] * 64 + sw * 8]) = ar[c];
        }
        #pragma unroll
        for (int c = 0; c < 2; ++c) {
            int sw = kcb[c] ^ (rowb[c] & 7);
            *reinterpret_cast<uint4*>(&Bs[rowb[c] * 64 + sw * 8]) = br[c];
        }
        __syncthreads();
        if (k0 + 64 < 1024) load_tiles(k0 + 64);
        #pragma unroll
        for (int ks = 0; ks < 2; ++ks) {
            bf16x8 af[4], bfr[2];
            #pragma unroll
            for (int i = 0; i < 4; ++i) {
                int ra = wm * 64 + i * 16 + fr;
                af[i] = *reinterpret_cast<const bf16x8*>(
                    &As[ra * 64 + (((ks * 4 + fk) ^ (ra & 7)) << 3)]);
            }
            #pragma unroll
            for (int j = 0; j < 2; ++j) {
                int rb = wn * 32 + j * 16 + fr;
                bfr[j] = *reinterpret_cast<const bf16x8*>(
                    &Bs[rb * 64 + (((ks * 4 + fk) ^ (rb & 7)) << 3)]);
            }
            #pragma unroll
            for (int i = 0; i < 4; ++i)
                #pragma unroll
                for (int j = 0; j < 2; ++j)
                    acc[i][j] = __builtin_amdgcn_mfma_f32_16x16x32_bf16(
                        af[i], bfr[j], acc[i][j], 0, 0, 0);
        }
    }

    #pragma unroll
    for (int i = 0; i < 4; ++i) {
        int row0 = wm * 64 + i * 16 + fk * 4;
        #pragma unroll
        for (int j = 0; j < 2; ++j) {
            int col = wn * 32 + j * 16 + fr;
            float bt = btag[col];
            #pragma unroll
            for (int r = 0; r < 4; ++r)
                ts[(row0 + r) * 65 + col] = acc[i][j][r] + bt;
        }
    }
    __syncthreads();

    if (tid < 128) {
        const float* rowp = ts + tid * 65;
        float mx = rowp[0];
        #pragma unroll 16
        for (int c = 1; c < 64; ++c) mx = fmaxf(mx, rowp[c]);
        float ssum = 0.f;
        #pragma unroll 16
        for (int c = 0; c < 64; ++c) ssum += __expf(rowp[c] - mx);
        const float lse = mx + logf(ssum);
        float* op = out + (size_t)(m0 + tid) * 64;
        #pragma unroll 16
        for (int c = 0; c < 64; ++c) op[c] = rowp[c] - lse;
    }
}

// ---------------------------------------------------------------------------
extern "C" void kernel_launch(void* const* d_in, const int* in_sizes, int n_in,
                              void* d_out, int out_size, void* d_ws, size_t ws_size,
                              hipStream_t stream)
{
    const int*   char_idx = (const int*)  d_in[0];
    const int*   word_idx = (const int*)  d_in[1];
    const float* Wemb     = (const float*)d_in[2];
    const float* Wec      = (const float*)d_in[3];
    const float* Wihc     = (const float*)d_in[4];
    const float* Whhc     = (const float*)d_in[5];
    const float* bihc     = (const float*)d_in[6];
    const float* bhhc     = (const float*)d_in[7];
    const float* Wih      = (const float*)d_in[8];
    const float* Whh      = (const float*)d_in[9];
    const float* bih      = (const float*)d_in[10];
    const float* bhh      = (const float*)d_in[11];
    const float* Wtag     = (const float*)d_in[12];
    const float* btag     = (const float*)d_in[13];
    float* out = (float*)d_out;

    // Workspace layout (~92 MB), all segments 16B-aligned
    char* w = (char*)d_ws;
    float*          precomp = (float*)w;            w += (size_t)SLEN * 4096 * 4;   // 64 MB
    unsigned short* Wihb    = (unsigned short*)w;   w += (size_t)4096 * 1280 * 2;   // 10.5 MB
    unsigned short* Xw      = (unsigned short*)w;   w += (size_t)4096 * 1280 * 2;   // 10.5 MB
    unsigned*       hs_b    = (unsigned*)w;         w += (size_t)SLEN * 512 * 4;    // 8 MB
    unsigned short* Wt      = (unsigned short*)w;   w += (size_t)32 * 1024 * 8 * 2; // 512 KB
    float*          table   = (float*)w;            w += 26 * 1024 * 4 + 1920;      // ~106 KB
    unsigned short* Wtagb   = (unsigned short*)w;   w += (size_t)64 * 1024 * 2;     // 128 KB
    unsigned*       hdata   = (unsigned*)w;         w += 8 * 1024 * 4;              // tagged h
    int*            xcd_ctr = (int*)w;              w += 32 * 4;
    int*            done    = (int*)w;

    // --- one launch: conversions/tables + Xw word-part + poisons + ctrs ---
    prep_all<<<4905, 256, 0, stream>>>(Wih, Wihb, Wec, Wihc, bihc, bhhc, table,
                                       Whhc, Wt, Wtag, Wtagb, hdata, xcd_ctr,
                                       word_idx, Wemb, Xw, done);

    // --- char-level LSTM: ALL 12 steps; writes Xw cols 1024..1280 directly ---
    char_fused<<<128, 256, 0, stream>>>(char_idx, Wt, table, Xw);

    // --- fused: precomp GEMM (producer blocks) + word recurrence (consumers) ---
    word_mega<<<1280, 256, 0, stream>>>(precomp, Whh, hs_b, hdata, xcd_ctr,
                                        Xw, Wihb, bih, bhh, done);

    // --- tag projection + log_softmax ---
    tag_mfma<<<32, 256, 0, stream>>>(
        (const unsigned short*)hs_b, Wtagb, btag, out);
}

// Round 14
// 843.835 us; speedup vs baseline: 80.2467x; 80.2467x over previous
//
#include <hip/hip_runtime.h>
#include <hip/hip_bf16.h>

// Dims (fixed by the reference)
#define SLEN 4096
#define CLEN 12
#define ECD  256
#define HCD  256
#define ED   1024
#define HD   1024
#define TD   64
#define NSLOT 32          // WGs per XCD group (32 units each)
#define POLL_LIMIT 2048   // dead-group bailout << live runtime

typedef unsigned  uv4 __attribute__((ext_vector_type(4)));
typedef __attribute__((ext_vector_type(8))) short bf16x8;   // MFMA A/B frag
typedef __attribute__((ext_vector_type(4))) float f32x4;    // MFMA C/D frag

#if defined(__has_builtin)
#if __has_builtin(__builtin_amdgcn_sdot4)
#define HAVE_SDOT4 1
#endif
#if __has_builtin(__builtin_amdgcn_perm)
#define HAVE_PERM 1
#endif
#endif

#ifdef HAVE_PERM
#define PERM2(hi, lo) __builtin_amdgcn_perm((unsigned)(hi), (unsigned)(lo), 0x05040100u)
#else
#define PERM2(hi, lo) ((((unsigned)(lo)) & 0xFFFFu) | (((unsigned)(hi)) << 16))
#endif

// global -> LDS direct (16B/lane). LDS dest = wave-uniform base + lane*16.
#define GLOAD_LDS16(g, l)                                                    \
    __builtin_amdgcn_global_load_lds(                                        \
        (const __attribute__((address_space(1))) void*)(g),                  \
        (__attribute__((address_space(3))) void*)(l), 16, 0, 0)

__device__ __forceinline__ float sigmoidf_(float x) { return 1.f / (1.f + __expf(-x)); }
__device__ __forceinline__ float tanh_fast(float x) {
    float ax = fabsf(x);
    float e = __expf(2.f * ax);          // inf-safe
    float t = 1.f - 2.f / (e + 1.f);
    return copysignf(t, x);
}
__device__ __forceinline__ unsigned short bf16r(float f) {
    unsigned u = __float_as_uint(f);
    return (unsigned short)((u + 0x7FFFu + ((u >> 16) & 1u)) >> 16);
}

// ===========================================================================
// prep_all: all one-time conversions + control-buffer init in ONE launch.
//   [0,2560)     : Wih  f32 -> bf16
//   [2560,2664)  : char input table [26][1024] f32
//   [2664,2792)  : Whhc -> Wt (k-major, gate-blocked)
//   [2792,2824)  : Wtag -> bf16
//   [2824,2856)  : hdata tag-poison (0xFFFF0000)
//   [2856,4904)  : Xw word-part  (Wemb gather -> bf16, cols 0..1024)
//   4904         : xcd_ctr = 0
// ===========================================================================
__global__ __launch_bounds__(256) void prep_all(
    const float* __restrict__ Wih,  unsigned short* __restrict__ Wihb,
    const float* __restrict__ Wec,  const float* __restrict__ Wihc,
    const float* __restrict__ bihc, const float* __restrict__ bhhc,
    float* __restrict__ table,
    const float* __restrict__ Whhc, unsigned short* __restrict__ Wt,
    const float* __restrict__ Wtag, unsigned short* __restrict__ Wtagb,
    unsigned* __restrict__ hdata, int* __restrict__ xcd_ctr,
    const int* __restrict__ word_idx, const float* __restrict__ Wemb,
    unsigned short* __restrict__ Xw)
{
    const int b = blockIdx.x, tid = threadIdx.x;
    if (b < 2560) {
        int i = b * 256 + tid;
        const float4* s = reinterpret_cast<const float4*>(Wih + (size_t)i * 8);
        float4 a = s[0], b2 = s[1];
        unsigned short o[8] = { bf16r(a.x), bf16r(a.y), bf16r(a.z), bf16r(a.w),
                                bf16r(b2.x), bf16r(b2.y), bf16r(b2.z), bf16r(b2.w) };
        *reinterpret_cast<uint4*>(Wihb + (size_t)i * 8) = *reinterpret_cast<uint4*>(o);
    } else if (b < 2664) {
        int id = (b - 2560) * 256 + tid;
        if (id < 26 * 1024) {
            int c = id >> 10, rp = id & 1023;
            int u = rp >> 2, g = rp & 3, row = g * 256 + u;
            const float4* a = reinterpret_cast<const float4*>(Wec + (size_t)c * 256);
            const float4* bb = reinterpret_cast<const float4*>(Wihc + (size_t)row * 256);
            float acc = 0.f;
            #pragma unroll 16
            for (int k = 0; k < 64; ++k) {
                float4 av = a[k], bv = bb[k];
                acc += av.x * bv.x + av.y * bv.y + av.z * bv.z + av.w * bv.w;
            }
            table[id] = acc + bihc[row] + bhhc[row];
        }
    } else if (b < 2792) {
        int id = (b - 2664) * 256 + tid;
        int C = id >> 5, kg = id & 31;
        int h = C >> 9, rem = C & 511, g = rem >> 7, ul = rem & 127;
        int row = g * 256 + h * 128 + ul;
        const float4* sv = reinterpret_cast<const float4*>(
            Whhc + (size_t)row * 256 + kg * 8);
        float4 a = sv[0], b2 = sv[1];
        unsigned short o[8] = { bf16r(a.x), bf16r(a.y), bf16r(a.z), bf16r(a.w),
                                bf16r(b2.x), bf16r(b2.y), bf16r(b2.z), bf16r(b2.w) };
        *reinterpret_cast<uint4*>(Wt + (size_t)(kg * 1024 + C) * 8) =
            *reinterpret_cast<uint4*>(o);
    } else if (b < 2824) {
        int i = (b - 2792) * 256 + tid;
        const float4* s = reinterpret_cast<const float4*>(Wtag + (size_t)i * 8);
        float4 a = s[0], b2 = s[1];
        unsigned short o[8] = { bf16r(a.x), bf16r(a.y), bf16r(a.z), bf16r(a.w),
                                bf16r(b2.x), bf16r(b2.y), bf16r(b2.z), bf16r(b2.w) };
        *reinterpret_cast<uint4*>(Wtagb + (size_t)i * 8) = *reinterpret_cast<uint4*>(o);
    } else if (b < 2856) {
        hdata[(b - 2824) * 256 + tid] = 0xFFFF0000u;   // tag 0xFFFF
    } else if (b < 4904) {
        int id = (b - 2856) * 256 + tid;              // 4096 rows x 128 chunks
        int row = id >> 7, c8 = id & 127;
        int k = c8 * 8;
        const float4* sv = reinterpret_cast<const float4*>(
            Wemb + (size_t)word_idx[row] * 1024 + k);
        float4 a = sv[0], b2 = sv[1];
        unsigned short o[8] = { bf16r(a.x), bf16r(a.y), bf16r(a.z), bf16r(a.w),
                                bf16r(b2.x), bf16r(b2.y), bf16r(b2.z), bf16r(b2.w) };
        *reinterpret_cast<uint4*>(Xw + (size_t)row * 1280 + k) =
            *reinterpret_cast<uint4*>(o);
    } else {
        if (tid < 8) xcd_ctr[tid] = 0;
    }
}

// ===========================================================================
// Fused char LSTM: ALL 12 steps, 128 WGs x 32 words. Epilogue writes the
// char half of Xw (cols 1024..1280) directly.
// ===========================================================================
__global__ __launch_bounds__(256) void char_fused(
    const int* __restrict__ char_idx,
    const unsigned short* __restrict__ Wt,   // [32 kg][1024 C][8] bf16
    const float* __restrict__ table,         // [26][1024]
    unsigned short* __restrict__ Xw)         // out [4096][1280], cols 1024..1280
{
    __shared__ unsigned short hA[2][8192];   // 2 x [32 words][256] bf16, swizzled
    __shared__ int cidx_s[32 * CLEN];

    const int tid  = threadIdx.x;
    const int lane = tid & 63;
    const int wv   = tid >> 6;       // wave 0..3
    const int fr   = lane & 15;
    const int fkq  = lane >> 4;      // 0..3
    const int w0   = blockIdx.x * 32;

    for (int e = tid; e < 32 * CLEN; e += 256)
        cidx_s[e] = char_idx[(w0 + (e / CLEN)) * CLEN + (e % CLEN)];
    {   // zero hA[0] (h_{-1} = 0)
        uint4 z; z.x = z.y = z.z = z.w = 0u;
        for (int e = tid; e < 1024; e += 256)
            *reinterpret_cast<uint4*>(&hA[0][e * 8]) = z;
    }
    __syncthreads();

    float cst[32];
    #pragma unroll
    for (int i = 0; i < 32; ++i) cst[i] = 0.f;

    for (int t = 0; t < CLEN; ++t) {
        const int cur = t & 1, nxt = cur ^ 1;
        #pragma unroll
        for (int h = 0; h < 2; ++h) {
            f32x4 acc[2][8];
            #pragma unroll
            for (int m = 0; m < 2; ++m)
                #pragma unroll
                for (int i = 0; i < 8; ++i) acc[m][i] = f32x4{0.f, 0.f, 0.f, 0.f};

            #pragma unroll
            for (int k0i = 0; k0i < 8; ++k0i) {
                const int kg = k0i * 4 + fkq;
                bf16x8 af[2];
                #pragma unroll
                for (int m = 0; m < 2; ++m) {
                    const int row = m * 16 + fr;
                    af[m] = *reinterpret_cast<const bf16x8*>(
                        &hA[cur][row * 256 + ((kg ^ ((row & 7) << 2)) << 3)]);
                }
                #pragma unroll
                for (int i = 0; i < 8; ++i) {
                    const int T = wv + (i << 2);               // tile 0..31
                    const int col = h * 512 + T * 16 + fr;     // gate-blocked col
                    const bf16x8 bf = *reinterpret_cast<const bf16x8*>(
                        Wt + (size_t)(kg * 1024 + col) * 8);
                    acc[0][i] = __builtin_amdgcn_mfma_f32_16x16x32_bf16(
                        af[0], bf, acc[0][i], 0, 0, 0);
                    acc[1][i] = __builtin_amdgcn_mfma_f32_16x16x32_bf16(
                        af[1], bf, acc[1][i], 0, 0, 0);
                }
            }

            // cell update: lane owns gates of 2 units x 8 words (i = 2g + ab)
            #pragma unroll
            for (int m = 0; m < 2; ++m) {
                #pragma unroll
                for (int r = 0; r < 4; ++r) {
                    const int wl = m * 16 + (lane >> 4) * 4 + r;  // word local
                    const int ci = cidx_s[wl * CLEN + t];
                    #pragma unroll
                    for (int ab = 0; ab < 2; ++ab) {
                        const int u = h * 128 + (wv + 4 * ab) * 16 + fr; // unit
                        const float4 tv = *reinterpret_cast<const float4*>(
                            table + (size_t)ci * 1024 + u * 4);
                        const int cix = ((h * 2 + m) * 2 + ab) * 4 + r;
                        const float gi_ = acc[m][0 + ab][r] + tv.x;
                        const float gf_ = acc[m][2 + ab][r] + tv.y;
                        const float gg_ = acc[m][4 + ab][r] + tv.z;
                        const float go_ = acc[m][6 + ab][r] + tv.w;
                        const float i_ = sigmoidf_(gi_), f_ = sigmoidf_(gf_);
                        const float g_ = tanh_fast(gg_), o_ = sigmoidf_(go_);
                        const float cn = f_ * cst[cix] + i_ * g_;
                        cst[cix] = cn;
                        const unsigned short hb = bf16r(o_ * tanh_fast(cn));
                        const int chn = u >> 3;
                        hA[nxt][wl * 256 + ((chn ^ ((wl & 7) << 2)) << 3) + (u & 7)] = hb;
                    }
                }
            }
        }
        __syncthreads();   // hA[nxt] complete before next step's GEMM
    }

    // final h (12 steps -> buffer 0) -> Xw cols 1024..1280, de-swizzled
    for (int e = tid; e < 1024; e += 256) {
        const int w = e >> 5, ch = e & 31;
        uint4 v = *reinterpret_cast<uint4*>(
            &hA[0][w * 256 + ((ch ^ ((w & 7) << 2)) << 3)]);
        *reinterpret_cast<uint4*>(
            Xw + (size_t)(w0 + w) * 1280 + 1024 + ch * 8) = v;
    }
}

// ===========================================================================
// Word input GEMM, m97-style: global_load_lds staging (16B/lane), LINEAR LDS,
// pre-swizzled per-lane GLOBAL source chunk (chunk^(row&7)); read side uses
// the same involution. C = A[M][K] @ B[N][K]^T + bias0 + bias1.
// (Standalone kernel — fusion with word_rec failed 3x: R8 spills, R10
//  fabric contention, R13 dispatch-order group collapse. Do not re-fuse.)
// ===========================================================================
__global__ __launch_bounds__(256) void gemm_bf16_bt(
    const unsigned short* __restrict__ A, const unsigned short* __restrict__ B,
    const float* __restrict__ bias0, const float* __restrict__ bias1,
    float* __restrict__ C, int M, int N, int K)
{
    __shared__ unsigned short As[128 * 64];
    __shared__ unsigned short Bs[128 * 64];
    const int tid  = threadIdx.x;
    const int lane = tid & 63;
    const int wv   = tid >> 6;
    const int wm = wv >> 1, wn = wv & 1;
    const int fr = lane & 15, fk = lane >> 4;
    const int n0 = blockIdx.x * 128;
    const int m0 = blockIdx.y * 128;

    // per-lane pre-swizzled global offsets + wave-uniform LDS bases
    int srcA[4], srcB[4];
    int ldsb[4];
    #pragma unroll
    for (int c = 0; c < 4; ++c) {
        int ch = c * 256 + wv * 64 + lane;
        int row = ch >> 3, chunk = ch & 7;
        int swc = chunk ^ (row & 7);
        srcA[c] = (m0 + row) * K + swc * 8;
        srcB[c] = (n0 + row) * K + swc * 8;
        ldsb[c] = (c * 256 + wv * 64) * 8;   // shorts; lane*8 added by HW
    }

    f32x4 acc[4][4];
    #pragma unroll
    for (int i = 0; i < 4; ++i)
        #pragma unroll
        for (int j = 0; j < 4; ++j) acc[i][j] = f32x4{0.f, 0.f, 0.f, 0.f};

    for (int k0 = 0; k0 < K; k0 += 64) {
        if (k0 > 0) __syncthreads();          // readers of previous tile done
        #pragma unroll
        for (int c = 0; c < 4; ++c) {
            GLOAD_LDS16(A + srcA[c] + k0, As + ldsb[c]);
            GLOAD_LDS16(B + srcB[c] + k0, Bs + ldsb[c]);
        }
        asm volatile("s_waitcnt vmcnt(0)" ::: "memory");
        __syncthreads();
        #pragma unroll
        for (int ks = 0; ks < 2; ++ks) {
            bf16x8 af[4], bfr[4];
            #pragma unroll
            for (int i = 0; i < 4; ++i) {
                int ra = wm * 64 + i * 16 + fr;
                af[i] = *reinterpret_cast<const bf16x8*>(
                    &As[ra * 64 + (((ks * 4 + fk) ^ (ra & 7)) << 3)]);
                int rb = wn * 64 + i * 16 + fr;
                bfr[i] = *reinterpret_cast<const bf16x8*>(
                    &Bs[rb * 64 + (((ks * 4 + fk) ^ (rb & 7)) << 3)]);
            }
            #pragma unroll
            for (int i = 0; i < 4; ++i)
                #pragma unroll
                for (int j = 0; j < 4; ++j)
                    acc[i][j] = __builtin_amdgcn_mfma_f32_16x16x32_bf16(
                        af[i], bfr[j], acc[i][j], 0, 0, 0);
        }
    }

    const int colb = n0 + wn * 64 + fr;
    float bsum[4];
    #pragma unroll
    for (int j = 0; j < 4; ++j) bsum[j] = bias0[colb + j * 16] + bias1[colb + j * 16];
    #pragma unroll
    for (int i = 0; i < 4; ++i) {
        int row0 = m0 + wm * 64 + i * 16 + fk * 4;
        #pragma unroll
        for (int j = 0; j < 4; ++j) {
            int col = colb + j * 16;
            #pragma unroll
            for (int r = 0; r < 4; ++r)
                C[(size_t)(row0 + r) * N + col] = acc[i][j][r] + bsum[j];
        }
    }
}

// ===========================================================================
// Word-level LSTM recurrence: int8 dot4 GEMV + single-trip self-validating
// tagged handoff, per-XCD redundant groups. (At 89% of the per-XCD int8-dot4
// VALU-issue floor — structurally converged.)
// ===========================================================================
__global__ __launch_bounds__(256, 1) void word_rec(
    const float* __restrict__ precomp, const float* __restrict__ W_hh,
    unsigned* __restrict__ hs_b, unsigned* hdata, int* xcd_ctr)
{
    const int tid  = threadIdx.x;
    const int v    = tid >> 6;
    const int lane = tid & 63;
    const int q    = lane >> 5;
    const int m    = lane & 31;
    const int j    = lane & 7;

    __shared__ int s_vals[2];
    if (tid == 0) {
        unsigned xcc;
        asm volatile("s_getreg_b32 %0, hwreg(HW_REG_XCC_ID)" : "=s"(xcc));
        xcc &= 7u;
        s_vals[0] = (int)xcc;
        s_vals[1] = atomicAdd(&xcd_ctr[xcc], 1);
    }
    __syncthreads();
    const int xcc  = s_vals[0];
    const int slot = s_vals[1];
    if (slot >= NSLOT) return;

    const int base_u = slot * 32 + v * 8;
    unsigned* hdata_x = hdata + xcc * 1024;   // 2 parities x 512 tagged dwords

    // --- W_hh slice -> int8 registers: 16 rows x 32 cols, per-row scale ---
    int   wq[16][8];
    float scl[16];
    #pragma unroll
    for (int r = 0; r < 16; ++r) {
        const int grow = (2 * q + (r >> 3)) * 1024 + base_u + (r & 7);
        const float4* rp = reinterpret_cast<const float4*>(
            W_hh + (size_t)grow * 1024 + 32 * m);
        float wv_[32];
        float mx = 0.f;
        #pragma unroll
        for (int d = 0; d < 8; ++d) {
            float4 f = rp[d];
            wv_[4*d+0] = f.x; wv_[4*d+1] = f.y; wv_[4*d+2] = f.z; wv_[4*d+3] = f.w;
            mx = fmaxf(mx, fmaxf(fmaxf(fabsf(f.x), fabsf(f.y)),
                                 fmaxf(fabsf(f.z), fabsf(f.w))));
        }
        mx = fmaxf(mx, __shfl_xor(mx, 1));
        mx = fmaxf(mx, __shfl_xor(mx, 2));
        mx = fmaxf(mx, __shfl_xor(mx, 4));
        mx = fmaxf(mx, __shfl_xor(mx, 8));
        mx = fmaxf(mx, __shfl_xor(mx, 16));
        const float inv = (mx > 0.f) ? (127.f / mx) : 0.f;
        scl[r] = mx * (1.f / (127.f * 127.f));
        #pragma unroll
        for (int d = 0; d < 8; ++d) {
            int b0 = (int)rintf(wv_[4*d+0] * inv) & 255;
            int b1 = (int)rintf(wv_[4*d+1] * inv) & 255;
            int b2 = (int)rintf(wv_[4*d+2] * inv) & 255;
            int b3 = (int)rintf(wv_[4*d+3] * inv) & 255;
            wq[r][d] = b0 | (b1 << 8) | (b2 << 16) | (b3 << 24);
        }
    }

#ifdef HAVE_SDOT4
    #define DOT4(a, b, c) __builtin_amdgcn_sdot4((a), (b), (c), false)
#else
    #define DOT4(a, b, c) ({ int _d; \
        asm("v_dot4_i32_i8 %0, %1, %2, %3" : "=v"(_d) : "v"(a), "v"(b), "v"(c)); _d; })
#endif

    float c_reg = 0.f;

    for (int t = 0; t < SLEN; ++t) {
        const int pp = (t + 1) & 1;
        const int pc = t & 1;

        // prefetch precomp gate biases (overlaps the poll wait)
        float pre0 = 0.f, pre1 = 0.f, pre2 = 0.f, pre3 = 0.f;
        if (lane < 8) {
            const float* pr = precomp + (size_t)t * 4096 + base_u + j;
            pre0 = pr[0]; pre1 = pr[1024]; pre2 = pr[2048]; pre3 = pr[3072];
        }

        // --- single-trip acquire: poll 16 tagged dwords (units 32m..32m+32) ---
        int hq[8];
        if (t > 0) {
            const unsigned tw = ((unsigned)(t - 1)) << 16;
            const unsigned* dp = hdata_x + pp * 512 + 16 * m;
            uv4 w0_, w1_, w2_, w3_;
            int it = 0; bool dead = false;
            for (;;) {
                asm volatile(
                    "global_load_dwordx4 %0, %4, off sc0\n\t"
                    "global_load_dwordx4 %1, %4, off offset:16 sc0\n\t"
                    "global_load_dwordx4 %2, %4, off offset:32 sc0\n\t"
                    "global_load_dwordx4 %3, %4, off offset:48 sc0\n\t"
                    "s_waitcnt vmcnt(0)"
                    : "=&v"(w0_), "=&v"(w1_), "=&v"(w2_), "=&v"(w3_)
                    : "v"(dp) : "memory");
                unsigned bad =
                    (w0_.x ^ tw) | (w0_.y ^ tw) | (w0_.z ^ tw) | (w0_.w ^ tw) |
                    (w1_.x ^ tw) | (w1_.y ^ tw) | (w1_.z ^ tw) | (w1_.w ^ tw) |
                    (w2_.x ^ tw) | (w2_.y ^ tw) | (w2_.z ^ tw) | (w2_.w ^ tw) |
                    (w3_.x ^ tw) | (w3_.y ^ tw) | (w3_.z ^ tw) | (w3_.w ^ tw);
                if (__all((bad & 0xFFFF0000u) == 0u)) break;
                if (++it > POLL_LIMIT) { dead = true; break; }
            }
            if (dead) return;
            hq[0] = (int)PERM2(w0_.y, w0_.x);
            hq[1] = (int)PERM2(w0_.w, w0_.z);
            hq[2] = (int)PERM2(w1_.y, w1_.x);
            hq[3] = (int)PERM2(w1_.w, w1_.z);
            hq[4] = (int)PERM2(w2_.y, w2_.x);
            hq[5] = (int)PERM2(w2_.w, w2_.z);
            hq[6] = (int)PERM2(w3_.y, w3_.x);
            hq[7] = (int)PERM2(w3_.w, w3_.z);
        } else {
            #pragma unroll
            for (int i = 0; i < 8; ++i) hq[i] = 0;
        }

        // --- 16 rows: int8 dot4 (2 indep chains) + exact int32 butterfly ---
        float self = 0.f;
        #pragma unroll
        for (int r = 0; r < 16; ++r) {
            int a0 = 0, a1 = 0;
            #pragma unroll
            for (int d = 0; d < 4; ++d) {
                a0 = DOT4(wq[r][d],     hq[d],     a0);
                a1 = DOT4(wq[r][4 + d], hq[4 + d], a1);
            }
            int s = a0 + a1;
            s += __shfl_xor(s, 1);  s += __shfl_xor(s, 2);
            s += __shfl_xor(s, 4);  s += __shfl_xor(s, 8);
            s += __shfl_xor(s, 16);
            self = ((lane & 31) == r) ? (float)s * scl[r] : self;
        }

        const float gi = __shfl(self, j);
        const float gf = __shfl(self, 8 + j);
        const float gg = __shfl(self, 32 + j);
        const float go = __shfl(self, 40 + j);

        float h = 0.f;
        if (lane < 8) {
            const float i_ = sigmoidf_(gi + pre0);
            const float f_ = sigmoidf_(gf + pre1);
            const float g_ = tanh_fast(gg + pre2);
            const float o_ = sigmoidf_(go + pre3);
            c_reg = f_ * c_reg + i_ * g_;
            h = o_ * tanh_fast(c_reg);
        }

        // publish: bf16 pairs for tag stage + self-validating tagged int8 pairs
        const float hn = __shfl_down(h, 1);
        int qv = (int)rintf(fminf(fmaxf(h * 127.f, -127.f), 127.f));
        const int qn = __shfl(qv, lane | 1);
        if (lane < 8 && (lane & 1) == 0) {
            unsigned pb = (unsigned)bf16r(h) | ((unsigned)bf16r(hn) << 16);
            hs_b[(size_t)t * 512 + (base_u >> 1) + (lane >> 1)] = pb;
            unsigned pk = ((unsigned)t << 16) | ((unsigned)(qn & 255) << 8)
                        | (unsigned)(qv & 255);
            unsigned* dpw = hdata_x + pc * 512 + slot * 16 + v * 4 + (lane >> 1);
            asm volatile("global_store_dword %0, %1, off sc0"
                         :: "v"(dpw), "v"(pk) : "memory");
        }
    }
    #undef DOT4
}

// ===========================================================================
// Tag projection (MFMA) + fused log_softmax.
// ===========================================================================
__global__ __launch_bounds__(256) void tag_mfma(
    const unsigned short* __restrict__ A,     // hs_b as bf16 [4096][1024]
    const unsigned short* __restrict__ B,     // Wtagb [64][1024]
    const float* __restrict__ btag, float* __restrict__ out)
{
    __shared__ unsigned short As[128 * 64];
    __shared__ unsigned short Bs[64 * 64];
    __shared__ float ts[128 * 65];

    const int tid  = threadIdx.x;
    const int lane = tid & 63;
    const int wm = (tid >> 6) >> 1, wn = (tid >> 6) & 1;
    const int fr = lane & 15, fk = lane >> 4;
    const int m0 = blockIdx.x * 128;

    uint4 ar[4], br[2];
    int rowa[4], kca[4], rowb[2], kcb[2];
    #pragma unroll
    for (int c = 0; c < 4; ++c) {
        int ch = c * 256 + tid;
        rowa[c] = ch >> 3; kca[c] = ch & 7;
    }
    #pragma unroll
    for (int c = 0; c < 2; ++c) {
        int ch = c * 256 + tid;
        rowb[c] = ch >> 3; kcb[c] = ch & 7;
    }

    auto load_tiles = [&](int k0) {
        #pragma unroll
        for (int c = 0; c < 4; ++c)
            ar[c] = *reinterpret_cast<const uint4*>(
                A + (size_t)(m0 + rowa[c]) * 1024 + k0 + kca[c] * 8);
        #pragma unroll
        for (int c = 0; c < 2; ++c)
            br[c] = *reinterpret_cast<const uint4*>(
                B + (size_t)rowb[c] * 1024 + k0 + kcb[c] * 8);
    };

    f32x4 acc[4][2];
    #pragma unroll
    for (int i = 0; i < 4; ++i)
        #pragma unroll
        for (int j = 0; j < 2; ++j) acc[i][j] = f32x4{0.f, 0.f, 0.f, 0.f};

    load_tiles(0);
    for (int k0 = 0; k0 < 1024; k0 += 64) {
        __syncthreads();
        #pragma unroll
        for (int c = 0; c < 4; ++c) {
            int sw = kca[c] ^ (rowa[c] & 7);
            *reinterpret_cast<uint4*>(&As[rowa[c] * 64 + sw * 8]) = ar[c];
        }
        #pragma unroll
        for (int c = 0; c < 2; ++c) {
            int sw = kcb[c] ^ (rowb[c] & 7);
            *reinterpret_cast<uint4*>(&Bs[rowb[c] * 64 + sw * 8]) = br[c];
        }
        __syncthreads();
        if (k0 + 64 < 1024) load_tiles(k0 + 64);
        #pragma unroll
        for (int ks = 0; ks < 2; ++ks) {
            bf16x8 af[4], bfr[2];
            #pragma unroll
            for (int i = 0; i < 4; ++i) {
                int ra = wm * 64 + i * 16 + fr;
                af[i] = *reinterpret_cast<const bf16x8*>(
                    &As[ra * 64 + (((ks * 4 + fk) ^ (ra & 7)) << 3)]);
            }
            #pragma unroll
            for (int j = 0; j < 2; ++j) {
                int rb = wn * 32 + j * 16 + fr;
                bfr[j] = *reinterpret_cast<const bf16x8*>(
                    &Bs[rb * 64 + (((ks * 4 + fk) ^ (rb & 7)) << 3)]);
            }
            #pragma unroll
            for (int i = 0; i < 4; ++i)
                #pragma unroll
                for (int j = 0; j < 2; ++j)
                    acc[i][j] = __builtin_amdgcn_mfma_f32_16x16x32_bf16(
                        af[i], bfr[j], acc[i][j], 0, 0, 0);
        }
    }

    #pragma unroll
    for (int i = 0; i < 4; ++i) {
        int row0 = wm * 64 + i * 16 + fk * 4;
        #pragma unroll
        for (int j = 0; j < 2; ++j) {
            int col = wn * 32 + j * 16 + fr;
            float bt = btag[col];
            #pragma unroll
            for (int r = 0; r < 4; ++r)
                ts[(row0 + r) * 65 + col] = acc[i][j][r] + bt;
        }
    }
    __syncthreads();

    if (tid < 128) {
        const float* rowp = ts + tid * 65;
        float mx = rowp[0];
        #pragma unroll 16
        for (int c = 1; c < 64; ++c) mx = fmaxf(mx, rowp[c]);
        float ssum = 0.f;
        #pragma unroll 16
        for (int c = 0; c < 64; ++c) ssum += __expf(rowp[c] - mx);
        const float lse = mx + logf(ssum);
        float* op = out + (size_t)(m0 + tid) * 64;
        #pragma unroll 16
        for (int c = 0; c < 64; ++c) op[c] = rowp[c] - lse;
    }
}

// ---------------------------------------------------------------------------
extern "C" void kernel_launch(void* const* d_in, const int* in_sizes, int n_in,
                              void* d_out, int out_size, void* d_ws, size_t ws_size,
                              hipStream_t stream)
{
    const int*   char_idx = (const int*)  d_in[0];
    const int*   word_idx = (const int*)  d_in[1];
    const float* Wemb     = (const float*)d_in[2];
    const float* Wec      = (const float*)d_in[3];
    const float* Wihc     = (const float*)d_in[4];
    const float* Whhc     = (const float*)d_in[5];
    const float* bihc     = (const float*)d_in[6];
    const float* bhhc     = (const float*)d_in[7];
    const float* Wih      = (const float*)d_in[8];
    const float* Whh      = (const float*)d_in[9];
    const float* bih      = (const float*)d_in[10];
    const float* bhh      = (const float*)d_in[11];
    const float* Wtag     = (const float*)d_in[12];
    const float* btag     = (const float*)d_in[13];
    float* out = (float*)d_out;

    // Workspace layout (~92 MB), all segments 16B-aligned
    char* w = (char*)d_ws;
    float*          precomp = (float*)w;            w += (size_t)SLEN * 4096 * 4;   // 64 MB
    unsigned short* Wihb    = (unsigned short*)w;   w += (size_t)4096 * 1280 * 2;   // 10.5 MB
    unsigned short* Xw      = (unsigned short*)w;   w += (size_t)4096 * 1280 * 2;   // 10.5 MB
    unsigned*       hs_b    = (unsigned*)w;         w += (size_t)SLEN * 512 * 4;    // 8 MB
    unsigned short* Wt      = (unsigned short*)w;   w += (size_t)32 * 1024 * 8 * 2; // 512 KB
    float*          table   = (float*)w;            w += 26 * 1024 * 4 + 1920;      // ~106 KB
    unsigned short* Wtagb   = (unsigned short*)w;   w += (size_t)64 * 1024 * 2;     // 128 KB
    unsigned*       hdata   = (unsigned*)w;         w += 8 * 1024 * 4;              // tagged h
    int*            xcd_ctr = (int*)w;

    // --- one launch: conversions/tables + Xw word-part + hdata poison + ctr ---
    prep_all<<<4905, 256, 0, stream>>>(Wih, Wihb, Wec, Wihc, bihc, bhhc, table,
                                       Whhc, Wt, Wtag, Wtagb, hdata, xcd_ctr,
                                       word_idx, Wemb, Xw);

    // --- char-level LSTM: ALL 12 steps; writes Xw cols 1024..1280 directly ---
    char_fused<<<128, 256, 0, stream>>>(char_idx, Wt, table, Xw);

    // --- word input projection GEMM (global_load_lds staging) ---
    gemm_bf16_bt<<<dim3(32, 32), 256, 0, stream>>>(
        Xw, Wihb, bih, bhh, precomp, SLEN, 4096, 1280);

    // --- sequential word-level LSTM recurrence (single-trip tagged handoff) ---
    word_rec<<<256, 256, 0, stream>>>(precomp, Whh, hs_b, hdata, xcd_ctr);

    // --- tag projection + log_softmax ---
    tag_mfma<<<32, 256, 0, stream>>>(
        (const unsigned short*)hs_b, Wtagb, btag, out);
}

// Round 15
// 831.832 us; speedup vs baseline: 81.4047x; 1.0144x over previous
//
#include <hip/hip_runtime.h>
#include <hip/hip_bf16.h>

// Dims (fixed by the reference)
#define SLEN 4096
#define CLEN 12
#define ECD  256
#define HCD  256
#define ED   1024
#define HD   1024
#define TD   64
#define NSLOT 32          // WGs per XCD group (32 units each)
#define POLL_LIMIT 2048   // dead-group bailout << live runtime

typedef unsigned  uv4 __attribute__((ext_vector_type(4)));
typedef __attribute__((ext_vector_type(8))) short bf16x8;   // MFMA A/B frag
typedef __attribute__((ext_vector_type(4))) float f32x4;    // MFMA C/D frag

#if defined(__has_builtin)
#if __has_builtin(__builtin_amdgcn_sdot4)
#define HAVE_SDOT4 1
#endif
#if __has_builtin(__builtin_amdgcn_perm)
#define HAVE_PERM 1
#endif
#endif

#ifdef HAVE_PERM
#define PERM2(hi, lo) __builtin_amdgcn_perm((unsigned)(hi), (unsigned)(lo), 0x05040100u)
#else
#define PERM2(hi, lo) ((((unsigned)(lo)) & 0xFFFFu) | (((unsigned)(hi)) << 16))
#endif

// global -> LDS direct (16B/lane). LDS dest = wave-uniform base + lane*16.
#define GLOAD_LDS16(g, l)                                                    \
    __builtin_amdgcn_global_load_lds(                                        \
        (const __attribute__((address_space(1))) void*)(g),                  \
        (__attribute__((address_space(3))) void*)(l), 16, 0, 0)

__device__ __forceinline__ float sigmoidf_(float x) { return 1.f / (1.f + __expf(-x)); }
__device__ __forceinline__ float tanh_fast(float x) {
    float ax = fabsf(x);
    float e = __expf(2.f * ax);          // inf-safe
    float t = 1.f - 2.f / (e + 1.f);
    return copysignf(t, x);
}
__device__ __forceinline__ unsigned short bf16r(float f) {
    unsigned u = __float_as_uint(f);
    return (unsigned short)((u + 0x7FFFu + ((u >> 16) & 1u)) >> 16);
}

// ===========================================================================
// prep_all: all one-time conversions + control-buffer init in ONE launch.
//   [0,2560)     : Wih  f32 -> bf16
//   [2560,2664)  : char input table [26][1024] f32
//   [2664,2792)  : Whhc -> Wt (k-major, gate-blocked)
//   [2792,2824)  : Wtag -> bf16
//   [2824,2856)  : hdata tag-poison (0xFFFF0000)
//   [2856,4904)  : Xw word-part  (Wemb gather -> bf16, cols 0..1024)
//   4904         : xcd_ctr = 0
// ===========================================================================
__global__ __launch_bounds__(256) void prep_all(
    const float* __restrict__ Wih,  unsigned short* __restrict__ Wihb,
    const float* __restrict__ Wec,  const float* __restrict__ Wihc,
    const float* __restrict__ bihc, const float* __restrict__ bhhc,
    float* __restrict__ table,
    const float* __restrict__ Whhc, unsigned short* __restrict__ Wt,
    const float* __restrict__ Wtag, unsigned short* __restrict__ Wtagb,
    unsigned* __restrict__ hdata, int* __restrict__ xcd_ctr,
    const int* __restrict__ word_idx, const float* __restrict__ Wemb,
    unsigned short* __restrict__ Xw)
{
    const int b = blockIdx.x, tid = threadIdx.x;
    if (b < 2560) {
        int i = b * 256 + tid;
        const float4* s = reinterpret_cast<const float4*>(Wih + (size_t)i * 8);
        float4 a = s[0], b2 = s[1];
        unsigned short o[8] = { bf16r(a.x), bf16r(a.y), bf16r(a.z), bf16r(a.w),
                                bf16r(b2.x), bf16r(b2.y), bf16r(b2.z), bf16r(b2.w) };
        *reinterpret_cast<uint4*>(Wihb + (size_t)i * 8) = *reinterpret_cast<uint4*>(o);
    } else if (b < 2664) {
        int id = (b - 2560) * 256 + tid;
        if (id < 26 * 1024) {
            int c = id >> 10, rp = id & 1023;
            int u = rp >> 2, g = rp & 3, row = g * 256 + u;
            const float4* a = reinterpret_cast<const float4*>(Wec + (size_t)c * 256);
            const float4* bb = reinterpret_cast<const float4*>(Wihc + (size_t)row * 256);
            float acc = 0.f;
            #pragma unroll 16
            for (int k = 0; k < 64; ++k) {
                float4 av = a[k], bv = bb[k];
                acc += av.x * bv.x + av.y * bv.y + av.z * bv.z + av.w * bv.w;
            }
            table[id] = acc + bihc[row] + bhhc[row];
        }
    } else if (b < 2792) {
        int id = (b - 2664) * 256 + tid;
        int C = id >> 5, kg = id & 31;
        int h = C >> 9, rem = C & 511, g = rem >> 7, ul = rem & 127;
        int row = g * 256 + h * 128 + ul;
        const float4* sv = reinterpret_cast<const float4*>(
            Whhc + (size_t)row * 256 + kg * 8);
        float4 a = sv[0], b2 = sv[1];
        unsigned short o[8] = { bf16r(a.x), bf16r(a.y), bf16r(a.z), bf16r(a.w),
                                bf16r(b2.x), bf16r(b2.y), bf16r(b2.z), bf16r(b2.w) };
        *reinterpret_cast<uint4*>(Wt + (size_t)(kg * 1024 + C) * 8) =
            *reinterpret_cast<uint4*>(o);
    } else if (b < 2824) {
        int i = (b - 2792) * 256 + tid;
        const float4* s = reinterpret_cast<const float4*>(Wtag + (size_t)i * 8);
        float4 a = s[0], b2 = s[1];
        unsigned short o[8] = { bf16r(a.x), bf16r(a.y), bf16r(a.z), bf16r(a.w),
                                bf16r(b2.x), bf16r(b2.y), bf16r(b2.z), bf16r(b2.w) };
        *reinterpret_cast<uint4*>(Wtagb + (size_t)i * 8) = *reinterpret_cast<uint4*>(o);
    } else if (b < 2856) {
        hdata[(b - 2824) * 256 + tid] = 0xFFFF0000u;   // tag 0xFFFF
    } else if (b < 4904) {
        int id = (b - 2856) * 256 + tid;              // 4096 rows x 128 chunks
        int row = id >> 7, c8 = id & 127;
        int k = c8 * 8;
        const float4* sv = reinterpret_cast<const float4*>(
            Wemb + (size_t)word_idx[row] * 1024 + k);
        float4 a = sv[0], b2 = sv[1];
        unsigned short o[8] = { bf16r(a.x), bf16r(a.y), bf16r(a.z), bf16r(a.w),
                                bf16r(b2.x), bf16r(b2.y), bf16r(b2.z), bf16r(b2.w) };
        *reinterpret_cast<uint4*>(Xw + (size_t)row * 1280 + k) =
            *reinterpret_cast<uint4*>(o);
    } else {
        if (tid < 8) xcd_ctr[tid] = 0;
    }
}

// ===========================================================================
// Fused char LSTM: ALL 12 steps, 128 WGs x 32 words. Epilogue writes the
// char half of Xw (cols 1024..1280) directly. (L2-BW-bound on Wt stream,
// ~25-50us; each WG must touch all of Wt -> no further blocking possible.)
// ===========================================================================
__global__ __launch_bounds__(256) void char_fused(
    const int* __restrict__ char_idx,
    const unsigned short* __restrict__ Wt,   // [32 kg][1024 C][8] bf16
    const float* __restrict__ table,         // [26][1024]
    unsigned short* __restrict__ Xw)         // out [4096][1280], cols 1024..1280
{
    __shared__ unsigned short hA[2][8192];   // 2 x [32 words][256] bf16, swizzled
    __shared__ int cidx_s[32 * CLEN];

    const int tid  = threadIdx.x;
    const int lane = tid & 63;
    const int wv   = tid >> 6;       // wave 0..3
    const int fr   = lane & 15;
    const int fkq  = lane >> 4;      // 0..3
    const int w0   = blockIdx.x * 32;

    for (int e = tid; e < 32 * CLEN; e += 256)
        cidx_s[e] = char_idx[(w0 + (e / CLEN)) * CLEN + (e % CLEN)];
    {   // zero hA[0] (h_{-1} = 0)
        uint4 z; z.x = z.y = z.z = z.w = 0u;
        for (int e = tid; e < 1024; e += 256)
            *reinterpret_cast<uint4*>(&hA[0][e * 8]) = z;
    }
    __syncthreads();

    float cst[32];
    #pragma unroll
    for (int i = 0; i < 32; ++i) cst[i] = 0.f;

    for (int t = 0; t < CLEN; ++t) {
        const int cur = t & 1, nxt = cur ^ 1;
        #pragma unroll
        for (int h = 0; h < 2; ++h) {
            f32x4 acc[2][8];
            #pragma unroll
            for (int m = 0; m < 2; ++m)
                #pragma unroll
                for (int i = 0; i < 8; ++i) acc[m][i] = f32x4{0.f, 0.f, 0.f, 0.f};

            #pragma unroll
            for (int k0i = 0; k0i < 8; ++k0i) {
                const int kg = k0i * 4 + fkq;
                bf16x8 af[2];
                #pragma unroll
                for (int m = 0; m < 2; ++m) {
                    const int row = m * 16 + fr;
                    af[m] = *reinterpret_cast<const bf16x8*>(
                        &hA[cur][row * 256 + ((kg ^ ((row & 7) << 2)) << 3)]);
                }
                #pragma unroll
                for (int i = 0; i < 8; ++i) {
                    const int T = wv + (i << 2);               // tile 0..31
                    const int col = h * 512 + T * 16 + fr;     // gate-blocked col
                    const bf16x8 bf = *reinterpret_cast<const bf16x8*>(
                        Wt + (size_t)(kg * 1024 + col) * 8);
                    acc[0][i] = __builtin_amdgcn_mfma_f32_16x16x32_bf16(
                        af[0], bf, acc[0][i], 0, 0, 0);
                    acc[1][i] = __builtin_amdgcn_mfma_f32_16x16x32_bf16(
                        af[1], bf, acc[1][i], 0, 0, 0);
                }
            }

            // cell update: lane owns gates of 2 units x 8 words (i = 2g + ab)
            #pragma unroll
            for (int m = 0; m < 2; ++m) {
                #pragma unroll
                for (int r = 0; r < 4; ++r) {
                    const int wl = m * 16 + (lane >> 4) * 4 + r;  // word local
                    const int ci = cidx_s[wl * CLEN + t];
                    #pragma unroll
                    for (int ab = 0; ab < 2; ++ab) {
                        const int u = h * 128 + (wv + 4 * ab) * 16 + fr; // unit
                        const float4 tv = *reinterpret_cast<const float4*>(
                            table + (size_t)ci * 1024 + u * 4);
                        const int cix = ((h * 2 + m) * 2 + ab) * 4 + r;
                        const float gi_ = acc[m][0 + ab][r] + tv.x;
                        const float gf_ = acc[m][2 + ab][r] + tv.y;
                        const float gg_ = acc[m][4 + ab][r] + tv.z;
                        const float go_ = acc[m][6 + ab][r] + tv.w;
                        const float i_ = sigmoidf_(gi_), f_ = sigmoidf_(gf_);
                        const float g_ = tanh_fast(gg_), o_ = sigmoidf_(go_);
                        const float cn = f_ * cst[cix] + i_ * g_;
                        cst[cix] = cn;
                        const unsigned short hb = bf16r(o_ * tanh_fast(cn));
                        const int chn = u >> 3;
                        hA[nxt][wl * 256 + ((chn ^ ((wl & 7) << 2)) << 3) + (u & 7)] = hb;
                    }
                }
            }
        }
        __syncthreads();   // hA[nxt] complete before next step's GEMM
    }

    // final h (12 steps -> buffer 0) -> Xw cols 1024..1280, de-swizzled
    for (int e = tid; e < 1024; e += 256) {
        const int w = e >> 5, ch = e & 31;
        uint4 v = *reinterpret_cast<uint4*>(
            &hA[0][w * 256 + ((ch ^ ((w & 7) << 2)) << 3)]);
        *reinterpret_cast<uint4*>(
            Xw + (size_t)(w0 + w) * 1280 + 1024 + ch * 8) = v;
    }
}

// ===========================================================================
// Word input GEMM v2: T3-min double-buffered global_load_lds pipeline with
// T4 counted vmcnt (stage next tile BEFORE computing current; vmcnt(8)
// drains only the previous tile's 8 loads; raw s_barrier — per-wave counted
// wait + barrier collectively proves the tile complete). T1 bijective XCD
// block swizzle (nwg=1024 % 8 == 0). Pre-swizzled global source chunk
// (chunk^(row&7)), linear LDS dest, same involution on the read side.
// (Standalone kernel — fusion with word_rec failed 3x: R8/R10/R13.)
// ===========================================================================
__global__ __launch_bounds__(256) void gemm_bf16_bt(
    const unsigned short* __restrict__ A, const unsigned short* __restrict__ B,
    const float* __restrict__ bias0, const float* __restrict__ bias1,
    float* __restrict__ C, int M, int N, int K)
{
    __shared__ unsigned short As[2][128 * 64];   // 32 KB
    __shared__ unsigned short Bs[2][128 * 64];   // 32 KB
    const int tid  = threadIdx.x;
    const int lane = tid & 63;
    const int wv   = tid >> 6;
    const int wm = wv >> 1, wn = wv & 1;
    const int fr = lane & 15, fk = lane >> 4;

    // T1: bijective XCD-aware block remap (grid 32x32 = 1024 blocks)
    const int bid = blockIdx.y * 32 + blockIdx.x;
    const int bsw = (bid & 7) * 128 + (bid >> 3);
    const int n0 = (bsw & 31) * 128;
    const int m0 = (bsw >> 5) * 128;

    // per-lane pre-swizzled global offsets + wave-uniform LDS bases
    int srcA[4], srcB[4];
    int ldsb[4];
    #pragma unroll
    for (int c = 0; c < 4; ++c) {
        int ch = c * 256 + wv * 64 + lane;
        int row = ch >> 3, chunk = ch & 7;
        int swc = chunk ^ (row & 7);
        srcA[c] = (m0 + row) * K + swc * 8;
        srcB[c] = (n0 + row) * K + swc * 8;
        ldsb[c] = (c * 256 + wv * 64) * 8;   // shorts; lane*16B added by HW
    }

    auto stage = [&](int buf, int k0) {
        #pragma unroll
        for (int c = 0; c < 4; ++c) {
            GLOAD_LDS16(A + srcA[c] + k0, &As[buf][ldsb[c]]);
            GLOAD_LDS16(B + srcB[c] + k0, &Bs[buf][ldsb[c]]);
        }
    };

    f32x4 acc[4][4];
    #pragma unroll
    for (int i = 0; i < 4; ++i)
        #pragma unroll
        for (int j = 0; j < 4; ++j) acc[i][j] = f32x4{0.f, 0.f, 0.f, 0.f};

    const int NT = K / 64;                 // 20 K-tiles
    stage(0, 0);                           // prologue: 8 loads in flight
    for (int kt = 0; kt < NT; ++kt) {
        const int cur = kt & 1;
        if (kt + 1 < NT) {
            stage(cur ^ 1, (kt + 1) * 64);             // +8 loads (16 in flight)
            asm volatile("s_waitcnt vmcnt(8)" ::: "memory");  // drain prev tile
        } else {
            asm volatile("s_waitcnt vmcnt(0)" ::: "memory");  // final tile
        }
        __builtin_amdgcn_s_barrier();      // all waves: buf[cur] complete
        #pragma unroll
        for (int ks = 0; ks < 2; ++ks) {
            bf16x8 af[4], bfr[4];
            #pragma unroll
            for (int i = 0; i < 4; ++i) {
                int ra = wm * 64 + i * 16 + fr;
                af[i] = *reinterpret_cast<const bf16x8*>(
                    &As[cur][ra * 64 + (((ks * 4 + fk) ^ (ra & 7)) << 3)]);
                int rb = wn * 64 + i * 16 + fr;
                bfr[i] = *reinterpret_cast<const bf16x8*>(
                    &Bs[cur][rb * 64 + (((ks * 4 + fk) ^ (rb & 7)) << 3)]);
            }
            #pragma unroll
            for (int i = 0; i < 4; ++i)
                #pragma unroll
                for (int j = 0; j < 4; ++j)
                    acc[i][j] = __builtin_amdgcn_mfma_f32_16x16x32_bf16(
                        af[i], bfr[j], acc[i][j], 0, 0, 0);
        }
        if (kt + 2 < NT)
            __builtin_amdgcn_s_barrier();  // readers done before buf reuse
    }

    const int colb = n0 + wn * 64 + fr;
    float bsum[4];
    #pragma unroll
    for (int j = 0; j < 4; ++j) bsum[j] = bias0[colb + j * 16] + bias1[colb + j * 16];
    #pragma unroll
    for (int i = 0; i < 4; ++i) {
        int row0 = m0 + wm * 64 + i * 16 + fk * 4;
        #pragma unroll
        for (int j = 0; j < 4; ++j) {
            int col = colb + j * 16;
            #pragma unroll
            for (int r = 0; r < 4; ++r)
                C[(size_t)(row0 + r) * N + col] = acc[i][j][r] + bsum[j];
        }
    }
}

// ===========================================================================
// Word-level LSTM recurrence: int8 dot4 GEMV + single-trip self-validating
// tagged handoff, per-XCD redundant groups. (At 89% of the per-XCD int8-dot4
// VALU-issue floor — structurally converged; do not touch.)
// ===========================================================================
__global__ __launch_bounds__(256, 1) void word_rec(
    const float* __restrict__ precomp, const float* __restrict__ W_hh,
    unsigned* __restrict__ hs_b, unsigned* hdata, int* xcd_ctr)
{
    const int tid  = threadIdx.x;
    const int v    = tid >> 6;
    const int lane = tid & 63;
    const int q    = lane >> 5;
    const int m    = lane & 31;
    const int j    = lane & 7;

    __shared__ int s_vals[2];
    if (tid == 0) {
        unsigned xcc;
        asm volatile("s_getreg_b32 %0, hwreg(HW_REG_XCC_ID)" : "=s"(xcc));
        xcc &= 7u;
        s_vals[0] = (int)xcc;
        s_vals[1] = atomicAdd(&xcd_ctr[xcc], 1);
    }
    __syncthreads();
    const int xcc  = s_vals[0];
    const int slot = s_vals[1];
    if (slot >= NSLOT) return;

    const int base_u = slot * 32 + v * 8;
    unsigned* hdata_x = hdata + xcc * 1024;   // 2 parities x 512 tagged dwords

    // --- W_hh slice -> int8 registers: 16 rows x 32 cols, per-row scale ---
    int   wq[16][8];
    float scl[16];
    #pragma unroll
    for (int r = 0; r < 16; ++r) {
        const int grow = (2 * q + (r >> 3)) * 1024 + base_u + (r & 7);
        const float4* rp = reinterpret_cast<const float4*>(
            W_hh + (size_t)grow * 1024 + 32 * m);
        float wv_[32];
        float mx = 0.f;
        #pragma unroll
        for (int d = 0; d < 8; ++d) {
            float4 f = rp[d];
            wv_[4*d+0] = f.x; wv_[4*d+1] = f.y; wv_[4*d+2] = f.z; wv_[4*d+3] = f.w;
            mx = fmaxf(mx, fmaxf(fmaxf(fabsf(f.x), fabsf(f.y)),
                                 fmaxf(fabsf(f.z), fabsf(f.w))));
        }
        mx = fmaxf(mx, __shfl_xor(mx, 1));
        mx = fmaxf(mx, __shfl_xor(mx, 2));
        mx = fmaxf(mx, __shfl_xor(mx, 4));
        mx = fmaxf(mx, __shfl_xor(mx, 8));
        mx = fmaxf(mx, __shfl_xor(mx, 16));
        const float inv = (mx > 0.f) ? (127.f / mx) : 0.f;
        scl[r] = mx * (1.f / (127.f * 127.f));
        #pragma unroll
        for (int d = 0; d < 8; ++d) {
            int b0 = (int)rintf(wv_[4*d+0] * inv) & 255;
            int b1 = (int)rintf(wv_[4*d+1] * inv) & 255;
            int b2 = (int)rintf(wv_[4*d+2] * inv) & 255;
            int b3 = (int)rintf(wv_[4*d+3] * inv) & 255;
            wq[r][d] = b0 | (b1 << 8) | (b2 << 16) | (b3 << 24);
        }
    }

#ifdef HAVE_SDOT4
    #define DOT4(a, b, c) __builtin_amdgcn_sdot4((a), (b), (c), false)
#else
    #define DOT4(a, b, c) ({ int _d; \
        asm("v_dot4_i32_i8 %0, %1, %2, %3" : "=v"(_d) : "v"(a), "v"(b), "v"(c)); _d; })
#endif

    float c_reg = 0.f;

    for (int t = 0; t < SLEN; ++t) {
        const int pp = (t + 1) & 1;
        const int pc = t & 1;

        // prefetch precomp gate biases (overlaps the poll wait)
        float pre0 = 0.f, pre1 = 0.f, pre2 = 0.f, pre3 = 0.f;
        if (lane < 8) {
            const float* pr = precomp + (size_t)t * 4096 + base_u + j;
            pre0 = pr[0]; pre1 = pr[1024]; pre2 = pr[2048]; pre3 = pr[3072];
        }

        // --- single-trip acquire: poll 16 tagged dwords (units 32m..32m+32) ---
        int hq[8];
        if (t > 0) {
            const unsigned tw = ((unsigned)(t - 1)) << 16;
            const unsigned* dp = hdata_x + pp * 512 + 16 * m;
            uv4 w0_, w1_, w2_, w3_;
            int it = 0; bool dead = false;
            for (;;) {
                asm volatile(
                    "global_load_dwordx4 %0, %4, off sc0\n\t"
                    "global_load_dwordx4 %1, %4, off offset:16 sc0\n\t"
                    "global_load_dwordx4 %2, %4, off offset:32 sc0\n\t"
                    "global_load_dwordx4 %3, %4, off offset:48 sc0\n\t"
                    "s_waitcnt vmcnt(0)"
                    : "=&v"(w0_), "=&v"(w1_), "=&v"(w2_), "=&v"(w3_)
                    : "v"(dp) : "memory");
                unsigned bad =
                    (w0_.x ^ tw) | (w0_.y ^ tw) | (w0_.z ^ tw) | (w0_.w ^ tw) |
                    (w1_.x ^ tw) | (w1_.y ^ tw) | (w1_.z ^ tw) | (w1_.w ^ tw) |
                    (w2_.x ^ tw) | (w2_.y ^ tw) | (w2_.z ^ tw) | (w2_.w ^ tw) |
                    (w3_.x ^ tw) | (w3_.y ^ tw) | (w3_.z ^ tw) | (w3_.w ^ tw);
                if (__all((bad & 0xFFFF0000u) == 0u)) break;
                if (++it > POLL_LIMIT) { dead = true; break; }
            }
            if (dead) return;
            hq[0] = (int)PERM2(w0_.y, w0_.x);
            hq[1] = (int)PERM2(w0_.w, w0_.z);
            hq[2] = (int)PERM2(w1_.y, w1_.x);
            hq[3] = (int)PERM2(w1_.w, w1_.z);
            hq[4] = (int)PERM2(w2_.y, w2_.x);
            hq[5] = (int)PERM2(w2_.w, w2_.z);
            hq[6] = (int)PERM2(w3_.y, w3_.x);
            hq[7] = (int)PERM2(w3_.w, w3_.z);
        } else {
            #pragma unroll
            for (int i = 0; i < 8; ++i) hq[i] = 0;
        }

        // --- 16 rows: int8 dot4 (2 indep chains) + exact int32 butterfly ---
        float self = 0.f;
        #pragma unroll
        for (int r = 0; r < 16; ++r) {
            int a0 = 0, a1 = 0;
            #pragma unroll
            for (int d = 0; d < 4; ++d) {
                a0 = DOT4(wq[r][d],     hq[d],     a0);
                a1 = DOT4(wq[r][4 + d], hq[4 + d], a1);
            }
            int s = a0 + a1;
            s += __shfl_xor(s, 1);  s += __shfl_xor(s, 2);
            s += __shfl_xor(s, 4);  s += __shfl_xor(s, 8);
            s += __shfl_xor(s, 16);
            self = ((lane & 31) == r) ? (float)s * scl[r] : self;
        }

        const float gi = __shfl(self, j);
        const float gf = __shfl(self, 8 + j);
        const float gg = __shfl(self, 32 + j);
        const float go = __shfl(self, 40 + j);

        float h = 0.f;
        if (lane < 8) {
            const float i_ = sigmoidf_(gi + pre0);
            const float f_ = sigmoidf_(gf + pre1);
            const float g_ = tanh_fast(gg + pre2);
            const float o_ = sigmoidf_(go + pre3);
            c_reg = f_ * c_reg + i_ * g_;
            h = o_ * tanh_fast(c_reg);
        }

        // publish: bf16 pairs for tag stage + self-validating tagged int8 pairs
        const float hn = __shfl_down(h, 1);
        int qv = (int)rintf(fminf(fmaxf(h * 127.f, -127.f), 127.f));
        const int qn = __shfl(qv, lane | 1);
        if (lane < 8 && (lane & 1) == 0) {
            unsigned pb = (unsigned)bf16r(h) | ((unsigned)bf16r(hn) << 16);
            hs_b[(size_t)t * 512 + (base_u >> 1) + (lane >> 1)] = pb;
            unsigned pk = ((unsigned)t << 16) | ((unsigned)(qn & 255) << 8)
                        | (unsigned)(qv & 255);
            unsigned* dpw = hdata_x + pc * 512 + slot * 16 + v * 4 + (lane >> 1);
            asm volatile("global_store_dword %0, %1, off sc0"
                         :: "v"(dpw), "v"(pk) : "memory");
        }
    }
    #undef DOT4
}

// ===========================================================================
// Tag projection (MFMA) + fused log_softmax.
// ===========================================================================
__global__ __launch_bounds__(256) void tag_mfma(
    const unsigned short* __restrict__ A,     // hs_b as bf16 [4096][1024]
    const unsigned short* __restrict__ B,     // Wtagb [64][1024]
    const float* __restrict__ btag, float* __restrict__ out)
{
    __shared__ unsigned short As[128 * 64];
    __shared__ unsigned short Bs[64 * 64];
    __shared__ float ts[128 * 65];

    const int tid  = threadIdx.x;
    const int lane = tid & 63;
    const int wm = (tid >> 6) >> 1, wn = (tid >> 6) & 1;
    const int fr = lane & 15, fk = lane >> 4;
    const int m0 = blockIdx.x * 128;

    uint4 ar[4], br[2];
    int rowa[4], kca[4], rowb[2], kcb[2];
    #pragma unroll
    for (int c = 0; c < 4; ++c) {
        int ch = c * 256 + tid;
        rowa[c] = ch >> 3; kca[c] = ch & 7;
    }
    #pragma unroll
    for (int c = 0; c < 2; ++c) {
        int ch = c * 256 + tid;
        rowb[c] = ch >> 3; kcb[c] = ch & 7;
    }

    auto load_tiles = [&](int k0) {
        #pragma unroll
        for (int c = 0; c < 4; ++c)
            ar[c] = *reinterpret_cast<const uint4*>(
                A + (size_t)(m0 + rowa[c]) * 1024 + k0 + kca[c] * 8);
        #pragma unroll
        for (int c = 0; c < 2; ++c)
            br[c] = *reinterpret_cast<const uint4*>(
                B + (size_t)rowb[c] * 1024 + k0 + kcb[c] * 8);
    };

    f32x4 acc[4][2];
    #pragma unroll
    for (int i = 0; i < 4; ++i)
        #pragma unroll
        for (int j = 0; j < 2; ++j) acc[i][j] = f32x4{0.f, 0.f, 0.f, 0.f};

    load_tiles(0);
    for (int k0 = 0; k0 < 1024; k0 += 64) {
        __syncthreads();
        #pragma unroll
        for (int c = 0; c < 4; ++c) {
            int sw = kca[c] ^ (rowa[c] & 7);
            *reinterpret_cast<uint4*>(&As[rowa[c] * 64 + sw * 8]) = ar[c];
        }
        #pragma unroll
        for (int c = 0; c < 2; ++c) {
            int sw = kcb[c] ^ (rowb[c] & 7);
            *reinterpret_cast<uint4*>(&Bs[rowb[c] * 64 + sw * 8]) = br[c];
        }
        __syncthreads();
        if (k0 + 64 < 1024) load_tiles(k0 + 64);
        #pragma unroll
        for (int ks = 0; ks < 2; ++ks) {
            bf16x8 af[4], bfr[2];
            #pragma unroll
            for (int i = 0; i < 4; ++i) {
                int ra = wm * 64 + i * 16 + fr;
                af[i] = *reinterpret_cast<const bf16x8*>(
                    &As[ra * 64 + (((ks * 4 + fk) ^ (ra & 7)) << 3)]);
            }
            #pragma unroll
            for (int j = 0; j < 2; ++j) {
                int rb = wn * 32 + j * 16 + fr;
                bfr[j] = *reinterpret_cast<const bf16x8*>(
                    &Bs[rb * 64 + (((ks * 4 + fk) ^ (rb & 7)) << 3)]);
            }
            #pragma unroll
            for (int i = 0; i < 4; ++i)
                #pragma unroll
                for (int j = 0; j < 2; ++j)
                    acc[i][j] = __builtin_amdgcn_mfma_f32_16x16x32_bf16(
                        af[i], bfr[j], acc[i][j], 0, 0, 0);
        }
    }

    #pragma unroll
    for (int i = 0; i < 4; ++i) {
        int row0 = wm * 64 + i * 16 + fk * 4;
        #pragma unroll
        for (int j = 0; j < 2; ++j) {
            int col = wn * 32 + j * 16 + fr;
            float bt = btag[col];
            #pragma unroll
            for (int r = 0; r < 4; ++r)
                ts[(row0 + r) * 65 + col] = acc[i][j][r] + bt;
        }
    }
    __syncthreads();

    if (tid < 128) {
        const float* rowp = ts + tid * 65;
        float mx = rowp[0];
        #pragma unroll 16
        for (int c = 1; c < 64; ++c) mx = fmaxf(mx, rowp[c]);
        float ssum = 0.f;
        #pragma unroll 16
        for (int c = 0; c < 64; ++c) ssum += __expf(rowp[c] - mx);
        const float lse = mx + logf(ssum);
        float* op = out + (size_t)(m0 + tid) * 64;
        #pragma unroll 16
        for (int c = 0; c < 64; ++c) op[c] = rowp[c] - lse;
    }
}

// ---------------------------------------------------------------------------
extern "C" void kernel_launch(void* const* d_in, const int* in_sizes, int n_in,
                              void* d_out, int out_size, void* d_ws, size_t ws_size,
                              hipStream_t stream)
{
    const int*   char_idx = (const int*)  d_in[0];
    const int*   word_idx = (const int*)  d_in[1];
    const float* Wemb     = (const float*)d_in[2];
    const float* Wec      = (const float*)d_in[3];
    const float* Wihc     = (const float*)d_in[4];
    const float* Whhc     = (const float*)d_in[5];
    const float* bihc     = (const float*)d_in[6];
    const float* bhhc     = (const float*)d_in[7];
    const float* Wih      = (const float*)d_in[8];
    const float* Whh      = (const float*)d_in[9];
    const float* bih      = (const float*)d_in[10];
    const float* bhh      = (const float*)d_in[11];
    const float* Wtag     = (const float*)d_in[12];
    const float* btag     = (const float*)d_in[13];
    float* out = (float*)d_out;

    // Workspace layout (~92 MB), all segments 16B-aligned
    char* w = (char*)d_ws;
    float*          precomp = (float*)w;            w += (size_t)SLEN * 4096 * 4;   // 64 MB
    unsigned short* Wihb    = (unsigned short*)w;   w += (size_t)4096 * 1280 * 2;   // 10.5 MB
    unsigned short* Xw      = (unsigned short*)w;   w += (size_t)4096 * 1280 * 2;   // 10.5 MB
    unsigned*       hs_b    = (unsigned*)w;         w += (size_t)SLEN * 512 * 4;    // 8 MB
    unsigned short* Wt      = (unsigned short*)w;   w += (size_t)32 * 1024 * 8 * 2; // 512 KB
    float*          table   = (float*)w;            w += 26 * 1024 * 4 + 1920;      // ~106 KB
    unsigned short* Wtagb   = (unsigned short*)w;   w += (size_t)64 * 1024 * 2;     // 128 KB
    unsigned*       hdata   = (unsigned*)w;         w += 8 * 1024 * 4;              // tagged h
    int*            xcd_ctr = (int*)w;

    // --- one launch: conversions/tables + Xw word-part + hdata poison + ctr ---
    prep_all<<<4905, 256, 0, stream>>>(Wih, Wihb, Wec, Wihc, bihc, bhhc, table,
                                       Whhc, Wt, Wtag, Wtagb, hdata, xcd_ctr,
                                       word_idx, Wemb, Xw);

    // --- char-level LSTM: ALL 12 steps; writes Xw cols 1024..1280 directly ---
    char_fused<<<128, 256, 0, stream>>>(char_idx, Wt, table, Xw);

    // --- word input projection GEMM (double-buffered gload_lds pipeline) ---
    gemm_bf16_bt<<<dim3(32, 32), 256, 0, stream>>>(
        Xw, Wihb, bih, bhh, precomp, SLEN, 4096, 1280);

    // --- sequential word-level LSTM recurrence (single-trip tagged handoff) ---
    word_rec<<<256, 256, 0, stream>>>(precomp, Whh, hs_b, hdata, xcd_ctr);

    // --- tag projection + log_softmax ---
    tag_mfma<<<32, 256, 0, stream>>>(
        (const unsigned short*)hs_b, Wtagb, btag, out);
}